// Round 9
// baseline (881.086 us; speedup 1.0000x reference)
//
#include <hip/hip_runtime.h>
#include <math.h>

#define NN 100000
#define NE 1600000
#define DD 128
#define NL 3
#define LN_EPS 1e-5f

typedef __attribute__((ext_vector_type(8))) short bf16x8;
typedef __attribute__((ext_vector_type(4))) float f32x4;
typedef unsigned short ushort_t;

__device__ __forceinline__ short f2bf(float f) {
  unsigned u = __float_as_uint(f);
  unsigned r = (u + 0x7fffu + ((u >> 16) & 1u)) >> 16;
  return (short)r;
}
__device__ __forceinline__ float bf2f(short s) {
  return __uint_as_float(((unsigned)(unsigned short)s) << 16);
}
__device__ __forceinline__ unsigned short f2h(float f) {
  _Float16 h = (_Float16)f;
  unsigned short u;
  __builtin_memcpy(&u, &h, 2);
  return u;
}
__device__ __forceinline__ float h2f(unsigned short u) {
  _Float16 h;
  __builtin_memcpy(&h, &u, 2);
  return (float)h;
}
__device__ __forceinline__ float gelu_exact(float x) {
  return 0.5f * x * (1.0f + erff(x * 0.7071067811865476f));
}

// ---------------- CSR build ----------------
__global__ void k_count(const int* __restrict__ dst, int* __restrict__ deg) {
  int e = blockIdx.x * blockDim.x + threadIdx.x;
  if (e < NE) atomicAdd(&deg[dst[e]], 1);
}

__global__ void k_block_sums(const int* __restrict__ deg, int* __restrict__ bsum) {
  __shared__ int sh[256];
  int t = threadIdx.x;
  int base = blockIdx.x * 1024;
  int s = 0;
#pragma unroll
  for (int j = 0; j < 4; j++) {
    int idx = base + t * 4 + j;
    if (idx < NN) s += deg[idx];
  }
  sh[t] = s;
  __syncthreads();
  for (int off = 128; off > 0; off >>= 1) {
    if (t < off) sh[t] += sh[t + off];
    __syncthreads();
  }
  if (t == 0) bsum[blockIdx.x] = sh[0];
}

__global__ void k_scan_sums(int* __restrict__ bsum, int nb) {
  __shared__ int sh[128];
  int t = threadIdx.x;
  int v = (t < nb) ? bsum[t] : 0;
  int acc = v;
  sh[t] = v;
  __syncthreads();
  for (int off = 1; off < 128; off <<= 1) {
    int o = (t >= off) ? sh[t - off] : 0;
    __syncthreads();
    acc += o;
    sh[t] = acc;
    __syncthreads();
  }
  if (t < nb) bsum[t] = acc - v;  // exclusive
}

__global__ void k_scan_write(const int* __restrict__ deg, const int* __restrict__ bsum,
                             int* __restrict__ rowstart) {
  __shared__ int sh[256];
  int t = threadIdx.x;
  int base = blockIdx.x * 1024;
  int idx0 = base + t * 4;
  int v[4];
  int s = 0;
#pragma unroll
  for (int j = 0; j < 4; j++) {
    int idx = idx0 + j;
    v[j] = (idx < NN) ? deg[idx] : 0;
    s += v[j];
  }
  int acc = s;
  sh[t] = s;
  __syncthreads();
  for (int off = 1; off < 256; off <<= 1) {
    int o = (t >= off) ? sh[t - off] : 0;
    __syncthreads();
    acc += o;
    sh[t] = acc;
    __syncthreads();
  }
  int excl = acc - s + bsum[blockIdx.x];
#pragma unroll
  for (int j = 0; j < 4; j++) {
    int idx = idx0 + j;
    if (idx < NN) rowstart[idx] = excl;
    excl += v[j];
  }
  if (blockIdx.x == 0 && t == 0) rowstart[NN] = NE;
}

__global__ void k_fill(const int* __restrict__ src, const int* __restrict__ dst,
                       const int* __restrict__ rowstart, int* __restrict__ cursor,
                       int* __restrict__ csr) {
  int e = blockIdx.x * blockDim.x + threadIdx.x;
  if (e < NE) {
    int d = dst[e];
    int p = atomicAdd(&cursor[d], 1);
    csr[rowstart[d] + p] = src[e];
  }
}

// ---------------- W pre-pack into MFMA B-fragment order (split bf16) ---------
__global__ void k_pack(const float* __restrict__ W1, const float* __restrict__ W2,
                       const float* __restrict__ pW, short* __restrict__ hi,
                       short* __restrict__ lo) {
  int id = blockIdx.x * 256 + threadIdx.x;  // 7*16384
  int m = id >> 14;                         // 0..6
  int r = id & 16383;
  const float* src;
  if (m == 6)
    src = pW;
  else {
    int layer = m >> 1;
    src = (m & 1) ? (W2 + layer * 16384) : (W1 + layer * 16384);
  }
  int j = r & 7;
  int l = (r >> 3) & 63;
  int kk = (r >> 9) & 3;
  int t = r >> 11;
  int k = kk * 32 + ((l >> 4) << 3) + j;
  int n = t * 16 + (l & 15);
  float w = src[k * DD + n];
  short h = f2bf(w);
  hi[id] = h;
  lo[id] = f2bf(w - bf2f(h));
}

// ---------------- x -> fp16 shadow ----------------
__global__ void k_cast(const float* __restrict__ x, ushort_t* __restrict__ hb) {
  int i = blockIdx.x * 256 + threadIdx.x;  // over NN*DD/4
  if (i < NN * DD / 4) {
    float4 v = ((const float4*)x)[i];
    ushort4 o;
    o.x = f2h(v.x);
    o.y = f2h(v.y);
    o.z = f2h(v.z);
    o.w = f2h(v.w);
    ((ushort4*)hb)[i] = o;
  }
}

// ---- gather: z = (1+eps)*h[n] (fp32) + sum_{incoming} hb[src] (fp16) -> split bf16
__global__ __launch_bounds__(256) void k_gather(const float* __restrict__ hin,
                                                const ushort_t* __restrict__ hb,
                                                const int* __restrict__ rowstart,
                                                const int* __restrict__ csr,
                                                const float* __restrict__ eps, int layer,
                                                unsigned* __restrict__ zhi,
                                                unsigned* __restrict__ zlo) {
  int n = blockIdx.x * 4 + (threadIdx.x >> 6);
  int t = threadIdx.x & 63;  // column pair 0..63
  float2 sv = ((const float2*)(hin + (size_t)n * DD))[t];
  float e1 = 1.0f + eps[layer];
  float a0 = e1 * sv.x, a1 = e1 * sv.y;
  float b0 = 0.f, b1 = 0.f, c0 = 0.f, c1 = 0.f, d0 = 0.f, d1 = 0.f;
  const unsigned* hb2 = (const unsigned*)hb;
  int s = rowstart[n], e = rowstart[n + 1];
  int k = s;
  for (; k + 3 < e; k += 4) {
    int n0 = csr[k], n1 = csr[k + 1], n2 = csr[k + 2], n3 = csr[k + 3];
    unsigned v0 = hb2[(size_t)n0 * 64 + t];
    unsigned v1 = hb2[(size_t)n1 * 64 + t];
    unsigned v2 = hb2[(size_t)n2 * 64 + t];
    unsigned v3 = hb2[(size_t)n3 * 64 + t];
    a0 += h2f((ushort_t)(v0 & 0xffffu));
    a1 += h2f((ushort_t)(v0 >> 16));
    b0 += h2f((ushort_t)(v1 & 0xffffu));
    b1 += h2f((ushort_t)(v1 >> 16));
    c0 += h2f((ushort_t)(v2 & 0xffffu));
    c1 += h2f((ushort_t)(v2 >> 16));
    d0 += h2f((ushort_t)(v3 & 0xffffu));
    d1 += h2f((ushort_t)(v3 >> 16));
  }
  for (; k < e; k++) {
    unsigned v = hb2[(size_t)csr[k] * 64 + t];
    a0 += h2f((ushort_t)(v & 0xffffu));
    a1 += h2f((ushort_t)(v >> 16));
  }
  a0 += (b0 + c0) + d0;
  a1 += (b1 + c1) + d1;
  short h0 = f2bf(a0), h1 = f2bf(a1);
  short l0 = f2bf(a0 - bf2f(h0)), l1 = f2bf(a1 - bf2f(h1));
  unsigned ph = (unsigned)(ushort_t)h0 | ((unsigned)(ushort_t)h1 << 16);
  unsigned pl = (unsigned)(ushort_t)l0 | ((unsigned)(ushort_t)l1 << 16);
  zhi[(size_t)n * 64 + t] = ph;
  zlo[(size_t)n * 64 + t] = pl;
}

// ------- fused MLP, 2 row-tiles (32 rows) per wave ---------------------------
// relu(z@W1+b1)@W2+b2 -> LN -> gelu -> +hin; hsum.  last: fused final pre-LN.
__global__ __launch_bounds__(64, 2) void k_mlp(
    const ushort_t* __restrict__ zhi, const ushort_t* __restrict__ zlo,
    const short* __restrict__ B1h, const short* __restrict__ B1l,
    const short* __restrict__ B2h, const short* __restrict__ B2l,
    const float* __restrict__ b1, const float* __restrict__ b2,
    const float* __restrict__ lng, const float* __restrict__ lnb,
    const float* __restrict__ hin, float* __restrict__ hout, float* __restrict__ hsum,
    ushort_t* __restrict__ hbp, const float* __restrict__ pg, const float* __restrict__ pbv,
    ushort_t* __restrict__ zohi, ushort_t* __restrict__ zolo, int first, int last) {
  __shared__ __align__(16) unsigned tb[32 * 132];  // wave-private 32x128, stride 132
  int lane = threadIdx.x;
  int row0 = blockIdx.x * 32;
  int m = lane & 15;
  int quad = lane >> 4;
  int rA0 = row0 + m;
  int rA1 = row0 + 16 + m;

  // ---- GEMM1: z @ W1, two A-tiles per B stream
  {
    const bf16x8* Ah0 = (const bf16x8*)(zhi + (size_t)rA0 * DD);
    const bf16x8* Al0 = (const bf16x8*)(zlo + (size_t)rA0 * DD);
    const bf16x8* Ah1 = (const bf16x8*)(zhi + (size_t)rA1 * DD);
    const bf16x8* Al1 = (const bf16x8*)(zlo + (size_t)rA1 * DD);
    const bf16x8* Bh = (const bf16x8*)B1h;
    const bf16x8* Bl = (const bf16x8*)B1l;
    f32x4 acc0[8], acc1[8];
#pragma unroll
    for (int t = 0; t < 8; t++) {
      acc0[t] = (f32x4){0.f, 0.f, 0.f, 0.f};
      acc1[t] = (f32x4){0.f, 0.f, 0.f, 0.f};
    }
#pragma unroll
    for (int kk = 0; kk < 4; kk++) {
      bf16x8 ah0 = Ah0[kk * 4 + quad];
      bf16x8 al0 = Al0[kk * 4 + quad];
      bf16x8 ah1 = Ah1[kk * 4 + quad];
      bf16x8 al1 = Al1[kk * 4 + quad];
#pragma unroll
      for (int t = 0; t < 8; t++) {
        bf16x8 bh = Bh[(t * 4 + kk) * 64 + lane];
        bf16x8 bl = Bl[(t * 4 + kk) * 64 + lane];
        acc0[t] = __builtin_amdgcn_mfma_f32_16x16x32_bf16(ah0, bh, acc0[t], 0, 0, 0);
        acc0[t] = __builtin_amdgcn_mfma_f32_16x16x32_bf16(al0, bh, acc0[t], 0, 0, 0);
        acc0[t] = __builtin_amdgcn_mfma_f32_16x16x32_bf16(ah0, bl, acc0[t], 0, 0, 0);
        acc1[t] = __builtin_amdgcn_mfma_f32_16x16x32_bf16(ah1, bh, acc1[t], 0, 0, 0);
        acc1[t] = __builtin_amdgcn_mfma_f32_16x16x32_bf16(al1, bh, acc1[t], 0, 0, 0);
        acc1[t] = __builtin_amdgcn_mfma_f32_16x16x32_bf16(ah1, bl, acc1[t], 0, 0, 0);
      }
    }
    // bias + relu + split-bf16 -> LDS (C-layout)
#pragma unroll
    for (int t = 0; t < 8; t++) {
      float bb = b1[t * 16 + m];
#pragma unroll
      for (int r = 0; r < 4; r++) {
        float v0 = fmaxf(acc0[t][r] + bb, 0.f);
        short hv0 = f2bf(v0);
        short lv0 = f2bf(v0 - bf2f(hv0));
        tb[(quad * 4 + r) * 132 + t * 16 + m] =
            (unsigned)(ushort_t)hv0 | ((unsigned)(ushort_t)lv0 << 16);
        float v1 = fmaxf(acc1[t][r] + bb, 0.f);
        short hv1 = f2bf(v1);
        short lv1 = f2bf(v1 - bf2f(hv1));
        tb[(16 + quad * 4 + r) * 132 + t * 16 + m] =
            (unsigned)(ushort_t)hv1 | ((unsigned)(ushort_t)lv1 << 16);
      }
    }
  }
  __syncthreads();  // single wave: trivial

  // ---- GEMM2: t @ W2, A-frags from LDS, two tiles
  const bf16x8* Bh = (const bf16x8*)B2h;
  const bf16x8* Bl = (const bf16x8*)B2l;
  f32x4 acc0[8], acc1[8];
#pragma unroll
  for (int t = 0; t < 8; t++) {
    acc0[t] = (f32x4){0.f, 0.f, 0.f, 0.f};
    acc1[t] = (f32x4){0.f, 0.f, 0.f, 0.f};
  }
#pragma unroll
  for (int kk = 0; kk < 4; kk++) {
    const uint4* tp0 = (const uint4*)(tb + m * 132 + kk * 32 + quad * 8);
    const uint4* tp1 = (const uint4*)(tb + (16 + m) * 132 + kk * 32 + quad * 8);
    uint4 w00 = tp0[0], w01 = tp0[1];
    uint4 w10 = tp1[0], w11 = tp1[1];
    unsigned ww0[8] = {w00.x, w00.y, w00.z, w00.w, w01.x, w01.y, w01.z, w01.w};
    unsigned ww1[8] = {w10.x, w10.y, w10.z, w10.w, w11.x, w11.y, w11.z, w11.w};
    bf16x8 ah0, al0, ah1, al1;
#pragma unroll
    for (int j = 0; j < 8; j++) {
      ah0[j] = (short)(ww0[j] & 0xffffu);
      al0[j] = (short)(ww0[j] >> 16);
      ah1[j] = (short)(ww1[j] & 0xffffu);
      al1[j] = (short)(ww1[j] >> 16);
    }
#pragma unroll
    for (int t = 0; t < 8; t++) {
      bf16x8 bh = Bh[(t * 4 + kk) * 64 + lane];
      bf16x8 bl = Bl[(t * 4 + kk) * 64 + lane];
      acc0[t] = __builtin_amdgcn_mfma_f32_16x16x32_bf16(ah0, bh, acc0[t], 0, 0, 0);
      acc0[t] = __builtin_amdgcn_mfma_f32_16x16x32_bf16(al0, bh, acc0[t], 0, 0, 0);
      acc0[t] = __builtin_amdgcn_mfma_f32_16x16x32_bf16(ah0, bl, acc0[t], 0, 0, 0);
      acc1[t] = __builtin_amdgcn_mfma_f32_16x16x32_bf16(ah1, bh, acc1[t], 0, 0, 0);
      acc1[t] = __builtin_amdgcn_mfma_f32_16x16x32_bf16(al1, bh, acc1[t], 0, 0, 0);
      acc1[t] = __builtin_amdgcn_mfma_f32_16x16x32_bf16(ah1, bl, acc1[t], 0, 0, 0);
    }
  }

  // ---- epilogue: bias + LN + gelu + residual; hsum / final-LN  (two tiles)
  float bb[8], gg[8], nb[8];
#pragma unroll
  for (int t = 0; t < 8; t++) {
    bb[t] = b2[t * 16 + m];
    gg[t] = lng[t * 16 + m];
    nb[t] = lnb[t * 16 + m];
  }
#pragma unroll
  for (int tile = 0; tile < 2; tile++) {
#pragma unroll
    for (int r = 0; r < 4; r++) {
      float u[8], s = 0.f, q = 0.f;
#pragma unroll
      for (int t = 0; t < 8; t++) {
        u[t] = (tile == 0 ? acc0[t][r] : acc1[t][r]) + bb[t];
        s += u[t];
        q += u[t] * u[t];
      }
#pragma unroll
      for (int mm = 1; mm < 16; mm <<= 1) {
        s += __shfl_xor(s, mm, 64);
        q += __shfl_xor(q, mm, 64);
      }
      float mean = s * (1.0f / DD);
      float var = q * (1.0f / DD) - mean * mean;
      float rstd = rsqrtf(var + LN_EPS);
      int row = row0 + tile * 16 + quad * 4 + r;
      if (!last) {
#pragma unroll
        for (int t = 0; t < 8; t++) {
          size_t idx = (size_t)row * DD + t * 16 + m;
          float z = (u[t] - mean) * rstd * gg[t] + nb[t];
          float o = gelu_exact(z) + hin[idx];
          hout[idx] = o;
          hbp[idx] = f2h(o);
          hsum[idx] = first ? o : (hsum[idx] + o);
        }
      } else {
        float w[8], s2 = 0.f, q2 = 0.f;
#pragma unroll
        for (int t = 0; t < 8; t++) {
          size_t idx = (size_t)row * DD + t * 16 + m;
          float z = (u[t] - mean) * rstd * gg[t] + nb[t];
          float o = gelu_exact(z) + hin[idx];
          w[t] = hsum[idx] + o;
          s2 += w[t];
          q2 += w[t] * w[t];
        }
#pragma unroll
        for (int mm = 1; mm < 16; mm <<= 1) {
          s2 += __shfl_xor(s2, mm, 64);
          q2 += __shfl_xor(q2, mm, 64);
        }
        float mean2 = s2 * (1.0f / DD);
        float var2 = q2 * (1.0f / DD) - mean2 * mean2;
        float rstd2 = rsqrtf(var2 + LN_EPS);
#pragma unroll
        for (int t = 0; t < 8; t++) {
          size_t idx = (size_t)row * DD + t * 16 + m;
          float v = (w[t] - mean2) * rstd2 * pg[t * 16 + m] + pbv[t * 16 + m];
          short hv = f2bf(v);
          zohi[idx] = (ushort_t)hv;
          zolo[idx] = (ushort_t)f2bf(v - bf2f(hv));
        }
      }
    }
  }
}

// ---------------- final GEMM: out = A*pW + pb (2 tiles / 32 rows per wave) ---
__global__ __launch_bounds__(64, 2) void k_mm(const ushort_t* __restrict__ Ahi,
                                              const ushort_t* __restrict__ Alo,
                                              const short* __restrict__ Bhi,
                                              const short* __restrict__ Blo,
                                              const float* __restrict__ bias,
                                              float* __restrict__ out) {
  int lane = threadIdx.x;
  int row0 = blockIdx.x * 32;
  int m = lane & 15;
  int quad = lane >> 4;
  int rA0 = row0 + m;
  int rA1 = row0 + 16 + m;
  const bf16x8* Ah0 = (const bf16x8*)(Ahi + (size_t)rA0 * DD);
  const bf16x8* Al0 = (const bf16x8*)(Alo + (size_t)rA0 * DD);
  const bf16x8* Ah1 = (const bf16x8*)(Ahi + (size_t)rA1 * DD);
  const bf16x8* Al1 = (const bf16x8*)(Alo + (size_t)rA1 * DD);
  const bf16x8* Bh = (const bf16x8*)Bhi;
  const bf16x8* Bl = (const bf16x8*)Blo;
  f32x4 acc0[8], acc1[8];
#pragma unroll
  for (int t = 0; t < 8; t++) {
    acc0[t] = (f32x4){0.f, 0.f, 0.f, 0.f};
    acc1[t] = (f32x4){0.f, 0.f, 0.f, 0.f};
  }
#pragma unroll
  for (int kk = 0; kk < 4; kk++) {
    bf16x8 ah0 = Ah0[kk * 4 + quad];
    bf16x8 al0 = Al0[kk * 4 + quad];
    bf16x8 ah1 = Ah1[kk * 4 + quad];
    bf16x8 al1 = Al1[kk * 4 + quad];
#pragma unroll
    for (int t = 0; t < 8; t++) {
      bf16x8 bh = Bh[(t * 4 + kk) * 64 + lane];
      bf16x8 bl = Bl[(t * 4 + kk) * 64 + lane];
      acc0[t] = __builtin_amdgcn_mfma_f32_16x16x32_bf16(ah0, bh, acc0[t], 0, 0, 0);
      acc0[t] = __builtin_amdgcn_mfma_f32_16x16x32_bf16(al0, bh, acc0[t], 0, 0, 0);
      acc0[t] = __builtin_amdgcn_mfma_f32_16x16x32_bf16(ah0, bl, acc0[t], 0, 0, 0);
      acc1[t] = __builtin_amdgcn_mfma_f32_16x16x32_bf16(ah1, bh, acc1[t], 0, 0, 0);
      acc1[t] = __builtin_amdgcn_mfma_f32_16x16x32_bf16(al1, bh, acc1[t], 0, 0, 0);
      acc1[t] = __builtin_amdgcn_mfma_f32_16x16x32_bf16(ah1, bl, acc1[t], 0, 0, 0);
    }
  }
  float bb[8];
#pragma unroll
  for (int t = 0; t < 8; t++) bb[t] = bias[t * 16 + m];
#pragma unroll
  for (int r = 0; r < 4; r++) {
    int row = row0 + quad * 4 + r;
#pragma unroll
    for (int t = 0; t < 8; t++) out[(size_t)row * DD + t * 16 + m] = acc0[t][r] + bb[t];
  }
#pragma unroll
  for (int r = 0; r < 4; r++) {
    int row = row0 + 16 + quad * 4 + r;
#pragma unroll
    for (int t = 0; t < 8; t++) out[(size_t)row * DD + t * 16 + m] = acc1[t][r] + bb[t];
  }
}

extern "C" void kernel_launch(void* const* d_in, const int* in_sizes, int n_in, void* d_out,
                              int out_size, void* d_ws, size_t ws_size, hipStream_t stream) {
  (void)in_sizes;
  (void)n_in;
  (void)out_size;
  (void)ws_size;
  const float* x = (const float*)d_in[0];
  const int* ei = (const int*)d_in[1];
  const float* W1 = (const float*)d_in[2];
  const float* b1 = (const float*)d_in[3];
  const float* W2 = (const float*)d_in[4];
  const float* b2 = (const float*)d_in[5];
  const float* eps = (const float*)d_in[6];
  const float* lng = (const float*)d_in[7];
  const float* lnb = (const float*)d_in[8];
  const float* plg = (const float*)d_in[9];
  const float* plb = (const float*)d_in[10];
  const float* pW = (const float*)d_in[11];
  const float* pb = (const float*)d_in[12];
  float* out = (float*)d_out;

  char* ws = (char*)d_ws;
  float* h = (float*)ws;
  ws += (size_t)NN * DD * 4;
  float* hs = (float*)ws;
  ws += (size_t)NN * DD * 4;
  ushort_t* zhi = (ushort_t*)ws;
  ws += (size_t)NN * DD * 2;
  ushort_t* zlo = (ushort_t*)ws;
  ws += (size_t)NN * DD * 2;
  ushort_t* hb = (ushort_t*)ws;
  ws += (size_t)NN * DD * 2;
  short* wphi = (short*)ws;
  ws += (size_t)7 * 16384 * 2;
  short* wplo = (short*)ws;
  ws += (size_t)7 * 16384 * 2;
  int* deg = (int*)ws;
  ws += (size_t)NN * 4;
  int* rowst = (int*)ws;
  ws += (size_t)(NN + 1) * 4 + 60;
  int* bsum = (int*)ws;
  ws += 512;
  int* csr = (int*)ws;
  ws += (size_t)NE * 4;

  const int* srcv = ei;
  const int* dstv = ei + NE;

  hipMemsetAsync(deg, 0, (size_t)NN * 4, stream);
  k_count<<<(NE + 255) / 256, 256, 0, stream>>>(dstv, deg);
  k_block_sums<<<98, 256, 0, stream>>>(deg, bsum);
  k_scan_sums<<<1, 128, 0, stream>>>(bsum, 98);
  k_scan_write<<<98, 256, 0, stream>>>(deg, bsum, rowst);
  hipMemsetAsync(deg, 0, (size_t)NN * 4, stream);  // reuse as cursor
  k_fill<<<(NE + 255) / 256, 256, 0, stream>>>(srcv, dstv, rowst, deg, csr);
  k_pack<<<448, 256, 0, stream>>>(W1, W2, pW, wphi, wplo);
  k_cast<<<(NN * DD / 4 + 255) / 256, 256, 0, stream>>>(x, hb);

  int mlp_grid = NN / 32;  // 3125, exact
  for (int l = 0; l < NL; l++) {
    const float* hin = (l == 0) ? x : h;
    k_gather<<<NN / 4, 256, 0, stream>>>(hin, hb, rowst, csr, eps, l, (unsigned*)zhi,
                                         (unsigned*)zlo);
    k_mlp<<<mlp_grid, 64, 0, stream>>>(
        zhi, zlo, wphi + (size_t)(2 * l) * 16384, wplo + (size_t)(2 * l) * 16384,
        wphi + (size_t)(2 * l + 1) * 16384, wplo + (size_t)(2 * l + 1) * 16384, b1 + l * DD,
        b2 + l * DD, lng + l * DD, lnb + l * DD, hin, h, hs, hb, plg, plb, zhi, zlo,
        l == 0 ? 1 : 0, l == NL - 1 ? 1 : 0);
  }
  k_mm<<<mlp_grid, 64, 0, stream>>>(zhi, zlo, wphi + (size_t)6 * 16384,
                                    wplo + (size_t)6 * 16384, pb, out);
}

// Round 10
// 764.984 us; speedup vs baseline: 1.1518x; 1.1518x over previous
//
#include <hip/hip_runtime.h>
#include <math.h>

#define NN 100000
#define NE 1600000
#define DD 128
#define NL 3
#define LN_EPS 1e-5f

typedef __attribute__((ext_vector_type(8))) short bf16x8;
typedef __attribute__((ext_vector_type(4))) float f32x4;
typedef unsigned short ushort_t;

__device__ __forceinline__ short f2bf(float f) {
  unsigned u = __float_as_uint(f);
  unsigned r = (u + 0x7fffu + ((u >> 16) & 1u)) >> 16;
  return (short)r;
}
__device__ __forceinline__ float bf2f(short s) {
  return __uint_as_float(((unsigned)(unsigned short)s) << 16);
}
__device__ __forceinline__ unsigned short f2h(float f) {
  _Float16 h = (_Float16)f;
  unsigned short u;
  __builtin_memcpy(&u, &h, 2);
  return u;
}
__device__ __forceinline__ float h2f(unsigned short u) {
  _Float16 h;
  __builtin_memcpy(&h, &u, 2);
  return (float)h;
}
__device__ __forceinline__ float gelu_exact(float x) {
  return 0.5f * x * (1.0f + erff(x * 0.7071067811865476f));
}

// ---------------- CSR build ----------------
__global__ void k_count(const int* __restrict__ dst, int* __restrict__ deg) {
  int e = blockIdx.x * blockDim.x + threadIdx.x;
  if (e < NE) atomicAdd(&deg[dst[e]], 1);
}

__global__ void k_block_sums(const int* __restrict__ deg, int* __restrict__ bsum) {
  __shared__ int sh[256];
  int t = threadIdx.x;
  int base = blockIdx.x * 1024;
  int s = 0;
#pragma unroll
  for (int j = 0; j < 4; j++) {
    int idx = base + t * 4 + j;
    if (idx < NN) s += deg[idx];
  }
  sh[t] = s;
  __syncthreads();
  for (int off = 128; off > 0; off >>= 1) {
    if (t < off) sh[t] += sh[t + off];
    __syncthreads();
  }
  if (t == 0) bsum[blockIdx.x] = sh[0];
}

__global__ void k_scan_sums(int* __restrict__ bsum, int nb) {
  __shared__ int sh[128];
  int t = threadIdx.x;
  int v = (t < nb) ? bsum[t] : 0;
  int acc = v;
  sh[t] = v;
  __syncthreads();
  for (int off = 1; off < 128; off <<= 1) {
    int o = (t >= off) ? sh[t - off] : 0;
    __syncthreads();
    acc += o;
    sh[t] = acc;
    __syncthreads();
  }
  if (t < nb) bsum[t] = acc - v;  // exclusive
}

__global__ void k_scan_write(const int* __restrict__ deg, const int* __restrict__ bsum,
                             int* __restrict__ rowstart) {
  __shared__ int sh[256];
  int t = threadIdx.x;
  int base = blockIdx.x * 1024;
  int idx0 = base + t * 4;
  int v[4];
  int s = 0;
#pragma unroll
  for (int j = 0; j < 4; j++) {
    int idx = idx0 + j;
    v[j] = (idx < NN) ? deg[idx] : 0;
    s += v[j];
  }
  int acc = s;
  sh[t] = s;
  __syncthreads();
  for (int off = 1; off < 256; off <<= 1) {
    int o = (t >= off) ? sh[t - off] : 0;
    __syncthreads();
    acc += o;
    sh[t] = acc;
    __syncthreads();
  }
  int excl = acc - s + bsum[blockIdx.x];
#pragma unroll
  for (int j = 0; j < 4; j++) {
    int idx = idx0 + j;
    if (idx < NN) rowstart[idx] = excl;
    excl += v[j];
  }
  if (blockIdx.x == 0 && t == 0) rowstart[NN] = NE;
}

__global__ void k_fill(const int* __restrict__ src, const int* __restrict__ dst,
                       const int* __restrict__ rowstart, int* __restrict__ cursor,
                       int* __restrict__ csr) {
  int e = blockIdx.x * blockDim.x + threadIdx.x;
  if (e < NE) {
    int d = dst[e];
    int p = atomicAdd(&cursor[d], 1);
    csr[rowstart[d] + p] = src[e];
  }
}

// ---------------- W pre-pack into MFMA B-fragment order (split bf16) ---------
__global__ void k_pack(const float* __restrict__ W1, const float* __restrict__ W2,
                       const float* __restrict__ pW, short* __restrict__ hi,
                       short* __restrict__ lo) {
  int id = blockIdx.x * 256 + threadIdx.x;  // 7*16384
  int m = id >> 14;                         // 0..6
  int r = id & 16383;
  const float* src;
  if (m == 6)
    src = pW;
  else {
    int layer = m >> 1;
    src = (m & 1) ? (W2 + layer * 16384) : (W1 + layer * 16384);
  }
  int j = r & 7;
  int l = (r >> 3) & 63;
  int kk = (r >> 9) & 3;
  int t = r >> 11;
  int k = kk * 32 + ((l >> 4) << 3) + j;
  int n = t * 16 + (l & 15);
  float w = src[k * DD + n];
  short h = f2bf(w);
  hi[id] = h;
  lo[id] = f2bf(w - bf2f(h));
}

// ---------------- x -> fp16 shadow ----------------
__global__ void k_cast(const float* __restrict__ x, ushort_t* __restrict__ hb) {
  int i = blockIdx.x * 256 + threadIdx.x;  // over NN*DD/4
  if (i < NN * DD / 4) {
    float4 v = ((const float4*)x)[i];
    ushort4 o;
    o.x = f2h(v.x);
    o.y = f2h(v.y);
    o.z = f2h(v.z);
    o.w = f2h(v.w);
    ((ushort4*)hb)[i] = o;
  }
}

// ---- gather: z = (1+eps)*h[n] (fp32) + sum_{incoming} hb[src] (fp16) -> split bf16
__global__ __launch_bounds__(256) void k_gather(const float* __restrict__ hin,
                                                const ushort_t* __restrict__ hb,
                                                const int* __restrict__ rowstart,
                                                const int* __restrict__ csr,
                                                const float* __restrict__ eps, int layer,
                                                unsigned* __restrict__ zhi,
                                                unsigned* __restrict__ zlo) {
  int n = blockIdx.x * 4 + (threadIdx.x >> 6);
  int t = threadIdx.x & 63;  // column pair 0..63
  float2 sv = ((const float2*)(hin + (size_t)n * DD))[t];
  float e1 = 1.0f + eps[layer];
  float a0 = e1 * sv.x, a1 = e1 * sv.y;
  float b0 = 0.f, b1 = 0.f, c0 = 0.f, c1 = 0.f, d0 = 0.f, d1 = 0.f;
  const unsigned* hb2 = (const unsigned*)hb;
  int s = rowstart[n], e = rowstart[n + 1];
  int k = s;
  for (; k + 3 < e; k += 4) {
    int n0 = csr[k], n1 = csr[k + 1], n2 = csr[k + 2], n3 = csr[k + 3];
    unsigned v0 = hb2[(size_t)n0 * 64 + t];
    unsigned v1 = hb2[(size_t)n1 * 64 + t];
    unsigned v2 = hb2[(size_t)n2 * 64 + t];
    unsigned v3 = hb2[(size_t)n3 * 64 + t];
    a0 += h2f((ushort_t)(v0 & 0xffffu));
    a1 += h2f((ushort_t)(v0 >> 16));
    b0 += h2f((ushort_t)(v1 & 0xffffu));
    b1 += h2f((ushort_t)(v1 >> 16));
    c0 += h2f((ushort_t)(v2 & 0xffffu));
    c1 += h2f((ushort_t)(v2 >> 16));
    d0 += h2f((ushort_t)(v3 & 0xffffu));
    d1 += h2f((ushort_t)(v3 >> 16));
  }
  for (; k < e; k++) {
    unsigned v = hb2[(size_t)csr[k] * 64 + t];
    a0 += h2f((ushort_t)(v & 0xffffu));
    a1 += h2f((ushort_t)(v >> 16));
  }
  a0 += (b0 + c0) + d0;
  a1 += (b1 + c1) + d1;
  short h0 = f2bf(a0), h1 = f2bf(a1);
  short l0 = f2bf(a0 - bf2f(h0)), l1 = f2bf(a1 - bf2f(h1));
  unsigned ph = (unsigned)(ushort_t)h0 | ((unsigned)(ushort_t)h1 << 16);
  unsigned pl = (unsigned)(ushort_t)l0 | ((unsigned)(ushort_t)l1 << 16);
  zhi[(size_t)n * 64 + t] = ph;
  zlo[(size_t)n * 64 + t] = pl;
}

// ------- fused MLP: relu(z@W1+b1)@W2+b2 -> LN -> gelu -> +hin ----------------
// R8-proven 1 wave / 16 rows. No hsum array: layers 1,2 write h+hb only;
// last layer reads h1 and computes hsum=(h1+h2)+h3 in registers -> final LN.
__global__ __launch_bounds__(64, 4) void k_mlp(
    const ushort_t* __restrict__ zhi, const ushort_t* __restrict__ zlo,
    const short* __restrict__ B1h, const short* __restrict__ B1l,
    const short* __restrict__ B2h, const short* __restrict__ B2l,
    const float* __restrict__ b1, const float* __restrict__ b2,
    const float* __restrict__ lng, const float* __restrict__ lnb,
    const float* __restrict__ hin, const float* __restrict__ hprev1,
    float* __restrict__ hout, ushort_t* __restrict__ hbp, const float* __restrict__ pg,
    const float* __restrict__ pbv, ushort_t* __restrict__ zohi, ushort_t* __restrict__ zolo,
    int last) {
  __shared__ __align__(16) unsigned tb[16 * 132];  // wave-private 16x128, stride 132
  int lane = threadIdx.x;
  int row0 = blockIdx.x * 16;
  int m = lane & 15;
  int quad = lane >> 4;
  int rA = row0 + m;

  // ---- GEMM1: z @ W1
  {
    const bf16x8* Ah = (const bf16x8*)(zhi + (size_t)rA * DD);
    const bf16x8* Al = (const bf16x8*)(zlo + (size_t)rA * DD);
    const bf16x8* Bh = (const bf16x8*)B1h;
    const bf16x8* Bl = (const bf16x8*)B1l;
    f32x4 acc[8];
#pragma unroll
    for (int t = 0; t < 8; t++) acc[t] = (f32x4){0.f, 0.f, 0.f, 0.f};
#pragma unroll
    for (int kk = 0; kk < 4; kk++) {
      bf16x8 ah = Ah[kk * 4 + quad];
      bf16x8 al = Al[kk * 4 + quad];
#pragma unroll
      for (int t = 0; t < 8; t++) {
        bf16x8 bh = Bh[(t * 4 + kk) * 64 + lane];
        bf16x8 bl = Bl[(t * 4 + kk) * 64 + lane];
        acc[t] = __builtin_amdgcn_mfma_f32_16x16x32_bf16(ah, bh, acc[t], 0, 0, 0);
        acc[t] = __builtin_amdgcn_mfma_f32_16x16x32_bf16(al, bh, acc[t], 0, 0, 0);
        acc[t] = __builtin_amdgcn_mfma_f32_16x16x32_bf16(ah, bl, acc[t], 0, 0, 0);
      }
    }
    // bias + relu + split-bf16 -> LDS (C-layout: row=quad*4+r, col=t*16+m)
#pragma unroll
    for (int t = 0; t < 8; t++) {
      float bb = b1[t * 16 + m];
#pragma unroll
      for (int r = 0; r < 4; r++) {
        float v = fmaxf(acc[t][r] + bb, 0.f);
        short hv = f2bf(v);
        short lv = f2bf(v - bf2f(hv));
        tb[(quad * 4 + r) * 132 + t * 16 + m] =
            (unsigned)(ushort_t)hv | ((unsigned)(ushort_t)lv << 16);
      }
    }
  }
  __syncthreads();  // single wave: trivial

  // ---- GEMM2: t @ W2, A-frags read from LDS in A-layout
  const bf16x8* Bh = (const bf16x8*)B2h;
  const bf16x8* Bl = (const bf16x8*)B2l;
  f32x4 acc[8];
#pragma unroll
  for (int t = 0; t < 8; t++) acc[t] = (f32x4){0.f, 0.f, 0.f, 0.f};
#pragma unroll
  for (int kk = 0; kk < 4; kk++) {
    const uint4* tp = (const uint4*)(tb + m * 132 + kk * 32 + quad * 8);
    uint4 w0 = tp[0], w1 = tp[1];
    unsigned ww[8] = {w0.x, w0.y, w0.z, w0.w, w1.x, w1.y, w1.z, w1.w};
    bf16x8 ah, al;
#pragma unroll
    for (int j = 0; j < 8; j++) {
      ah[j] = (short)(ww[j] & 0xffffu);
      al[j] = (short)(ww[j] >> 16);
    }
#pragma unroll
    for (int t = 0; t < 8; t++) {
      bf16x8 bh = Bh[(t * 4 + kk) * 64 + lane];
      bf16x8 bl = Bl[(t * 4 + kk) * 64 + lane];
      acc[t] = __builtin_amdgcn_mfma_f32_16x16x32_bf16(ah, bh, acc[t], 0, 0, 0);
      acc[t] = __builtin_amdgcn_mfma_f32_16x16x32_bf16(al, bh, acc[t], 0, 0, 0);
      acc[t] = __builtin_amdgcn_mfma_f32_16x16x32_bf16(ah, bl, acc[t], 0, 0, 0);
    }
  }

  // ---- epilogue: bias + LN + gelu + residual; h/hb or fused final-LN
  float bb[8], gg[8], nb[8];
#pragma unroll
  for (int t = 0; t < 8; t++) {
    bb[t] = b2[t * 16 + m];
    gg[t] = lng[t * 16 + m];
    nb[t] = lnb[t * 16 + m];
  }
#pragma unroll
  for (int r = 0; r < 4; r++) {
    float u[8], s = 0.f, q = 0.f;
#pragma unroll
    for (int t = 0; t < 8; t++) {
      u[t] = acc[t][r] + bb[t];
      s += u[t];
      q += u[t] * u[t];
    }
#pragma unroll
    for (int mm = 1; mm < 16; mm <<= 1) {
      s += __shfl_xor(s, mm, 64);
      q += __shfl_xor(q, mm, 64);
    }
    float mean = s * (1.0f / DD);
    float var = q * (1.0f / DD) - mean * mean;
    float rstd = rsqrtf(var + LN_EPS);
    int row = row0 + quad * 4 + r;
    if (!last) {
#pragma unroll
      for (int t = 0; t < 8; t++) {
        size_t idx = (size_t)row * DD + t * 16 + m;
        float z = (u[t] - mean) * rstd * gg[t] + nb[t];
        float o = gelu_exact(z) + hin[idx];
        hout[idx] = o;
        hbp[idx] = f2h(o);
      }
    } else {
      // hsum = (h1 + h2) + h3 in registers -> final pre-LN -> split bf16 z
      float w[8], s2 = 0.f, q2 = 0.f;
#pragma unroll
      for (int t = 0; t < 8; t++) {
        size_t idx = (size_t)row * DD + t * 16 + m;
        float h2v = hin[idx];
        float z = (u[t] - mean) * rstd * gg[t] + nb[t];
        float o = gelu_exact(z) + h2v;  // h3
        w[t] = (hprev1[idx] + h2v) + o;
        s2 += w[t];
        q2 += w[t] * w[t];
      }
#pragma unroll
      for (int mm = 1; mm < 16; mm <<= 1) {
        s2 += __shfl_xor(s2, mm, 64);
        q2 += __shfl_xor(q2, mm, 64);
      }
      float mean2 = s2 * (1.0f / DD);
      float var2 = q2 * (1.0f / DD) - mean2 * mean2;
      float rstd2 = rsqrtf(var2 + LN_EPS);
#pragma unroll
      for (int t = 0; t < 8; t++) {
        size_t idx = (size_t)row * DD + t * 16 + m;
        float v = (w[t] - mean2) * rstd2 * pg[t * 16 + m] + pbv[t * 16 + m];
        short hv = f2bf(v);
        zohi[idx] = (ushort_t)hv;
        zolo[idx] = (ushort_t)f2bf(v - bf2f(hv));
      }
    }
  }
}

// ---------------- final GEMM: out = A*pW + pb (1 wave / 16 rows) -------------
__global__ __launch_bounds__(64, 4) void k_mm(const ushort_t* __restrict__ Ahi,
                                              const ushort_t* __restrict__ Alo,
                                              const short* __restrict__ Bhi,
                                              const short* __restrict__ Blo,
                                              const float* __restrict__ bias,
                                              float* __restrict__ out) {
  int lane = threadIdx.x;
  int row0 = blockIdx.x * 16;
  int rA = row0 + (lane & 15);
  int quad = lane >> 4;
  const bf16x8* Ah = (const bf16x8*)(Ahi + (size_t)rA * DD);
  const bf16x8* Al = (const bf16x8*)(Alo + (size_t)rA * DD);
  const bf16x8* Bh = (const bf16x8*)Bhi;
  const bf16x8* Bl = (const bf16x8*)Blo;
  f32x4 acc[8];
#pragma unroll
  for (int t = 0; t < 8; t++) acc[t] = (f32x4){0.f, 0.f, 0.f, 0.f};
#pragma unroll
  for (int kk = 0; kk < 4; kk++) {
    bf16x8 ah = Ah[kk * 4 + quad];
    bf16x8 al = Al[kk * 4 + quad];
#pragma unroll
    for (int t = 0; t < 8; t++) {
      bf16x8 bh = Bh[(t * 4 + kk) * 64 + lane];
      bf16x8 bl = Bl[(t * 4 + kk) * 64 + lane];
      acc[t] = __builtin_amdgcn_mfma_f32_16x16x32_bf16(ah, bh, acc[t], 0, 0, 0);
      acc[t] = __builtin_amdgcn_mfma_f32_16x16x32_bf16(al, bh, acc[t], 0, 0, 0);
      acc[t] = __builtin_amdgcn_mfma_f32_16x16x32_bf16(ah, bl, acc[t], 0, 0, 0);
    }
  }
  int colb = lane & 15;
  float bb[8];
#pragma unroll
  for (int t = 0; t < 8; t++) bb[t] = bias[t * 16 + colb];
  int rowc0 = row0 + quad * 4;
#pragma unroll
  for (int r = 0; r < 4; r++) {
    int row = rowc0 + r;
#pragma unroll
    for (int t = 0; t < 8; t++) out[(size_t)row * DD + t * 16 + colb] = acc[t][r] + bb[t];
  }
}

extern "C" void kernel_launch(void* const* d_in, const int* in_sizes, int n_in, void* d_out,
                              int out_size, void* d_ws, size_t ws_size, hipStream_t stream) {
  (void)in_sizes;
  (void)n_in;
  (void)out_size;
  (void)ws_size;
  const float* x = (const float*)d_in[0];
  const int* ei = (const int*)d_in[1];
  const float* W1 = (const float*)d_in[2];
  const float* b1 = (const float*)d_in[3];
  const float* W2 = (const float*)d_in[4];
  const float* b2 = (const float*)d_in[5];
  const float* eps = (const float*)d_in[6];
  const float* lng = (const float*)d_in[7];
  const float* lnb = (const float*)d_in[8];
  const float* plg = (const float*)d_in[9];
  const float* plb = (const float*)d_in[10];
  const float* pW = (const float*)d_in[11];
  const float* pb = (const float*)d_in[12];
  float* out = (float*)d_out;

  char* ws = (char*)d_ws;
  float* h1 = (float*)ws;
  ws += (size_t)NN * DD * 4;
  float* h2 = (float*)ws;
  ws += (size_t)NN * DD * 4;
  ushort_t* zhi = (ushort_t*)ws;
  ws += (size_t)NN * DD * 2;
  ushort_t* zlo = (ushort_t*)ws;
  ws += (size_t)NN * DD * 2;
  ushort_t* hb = (ushort_t*)ws;
  ws += (size_t)NN * DD * 2;
  short* wphi = (short*)ws;
  ws += (size_t)7 * 16384 * 2;
  short* wplo = (short*)ws;
  ws += (size_t)7 * 16384 * 2;
  int* deg = (int*)ws;
  ws += (size_t)NN * 4;
  int* rowst = (int*)ws;
  ws += (size_t)(NN + 1) * 4 + 60;
  int* bsum = (int*)ws;
  ws += 512;
  int* csr = (int*)ws;
  ws += (size_t)NE * 4;

  const int* srcv = ei;
  const int* dstv = ei + NE;

  hipMemsetAsync(deg, 0, (size_t)NN * 4, stream);
  k_count<<<(NE + 255) / 256, 256, 0, stream>>>(dstv, deg);
  k_block_sums<<<98, 256, 0, stream>>>(deg, bsum);
  k_scan_sums<<<1, 128, 0, stream>>>(bsum, 98);
  k_scan_write<<<98, 256, 0, stream>>>(deg, bsum, rowst);
  hipMemsetAsync(deg, 0, (size_t)NN * 4, stream);  // reuse as cursor
  k_fill<<<(NE + 255) / 256, 256, 0, stream>>>(srcv, dstv, rowst, deg, csr);
  k_pack<<<448, 256, 0, stream>>>(W1, W2, pW, wphi, wplo);
  k_cast<<<(NN * DD / 4 + 255) / 256, 256, 0, stream>>>(x, hb);

  int mlp_grid = NN / 16;  // 6250, exact
  const float* hins[NL] = {x, h1, h2};
  float* houts[NL] = {h1, h2, nullptr};
  for (int l = 0; l < NL; l++) {
    k_gather<<<NN / 4, 256, 0, stream>>>(hins[l], hb, rowst, csr, eps, l, (unsigned*)zhi,
                                         (unsigned*)zlo);
    k_mlp<<<mlp_grid, 64, 0, stream>>>(
        zhi, zlo, wphi + (size_t)(2 * l) * 16384, wplo + (size_t)(2 * l) * 16384,
        wphi + (size_t)(2 * l + 1) * 16384, wplo + (size_t)(2 * l + 1) * 16384, b1 + l * DD,
        b2 + l * DD, lng + l * DD, lnb + l * DD, hins[l], h1, houts[l], hb, plg, plb, zhi, zlo,
        l == NL - 1 ? 1 : 0);
  }
  k_mm<<<mlp_grid, 64, 0, stream>>>(zhi, zlo, wphi + (size_t)6 * 16384,
                                    wplo + (size_t)6 * 16384, pb, out);
}